// Round 1
// baseline (20003.664 us; speedup 1.0000x reference)
//
#include <hip/hip_runtime.h>
#include <hip/hip_bf16.h>

// ESN recurrence on MI355X — R5: self-validating tagged publish.
// T=4096 steps, B=64, I=128, H=1024. out = h_T [64,1024] fp32.
//
// Key change vs R4: no flags, no producer store-ack, no epilogue barriers.
// Every published u32 (2 bf16 h-values) carries a generation tag in bit 30
// (= bit 14 of the odd bf16, provably 0 for tanh outputs |v|<=1.0).
// Consumers poll by loading the data itself and checking tags; the poll IS
// the data load. Tag sequence 1,1,0,0,... distinguishes generation t-1
// from t-3 and from the zeroed init in each double buffer.
// Raw s_barrier + lgkmcnt-only waits keep publish stores in flight across
// barriers (no vmcnt drain). h-loads issued before the x-phase so x-MFMAs
// hide load latency. Dual accumulator chains (hi/lo) halve dependent-MFMA
// stalls.

#define TT 4096
#define BB 64
#define II 128
#define HH 1024
#define TAGBIT 0x40000000u

typedef short bf16x8 __attribute__((ext_vector_type(8)));
typedef float f32x4 __attribute__((ext_vector_type(4)));
typedef unsigned int u32x4 __attribute__((ext_vector_type(4)));

__device__ __forceinline__ unsigned short f2bf(float f) {
    unsigned int u = __float_as_uint(f);
    u += 0x7FFFu + ((u >> 16) & 1u);   // RNE
    return (unsigned short)(u >> 16);
}
__device__ __forceinline__ float bf2f(unsigned short s) {
    return __uint_as_float(((unsigned int)s) << 16);
}

__device__ __forceinline__ u32x4 gload16_sc1(const unsigned int* p) {
    u32x4 r;
    asm volatile("global_load_dwordx4 %0, %1, off sc1"
                 : "=v"(r) : "v"(p) : "memory");
    return r;
}
__device__ __forceinline__ void gstore4_sc1(unsigned int* p, unsigned int v) {
    asm volatile("global_store_dword %0, %1, off sc1"
                 :: "v"(p), "v"(v) : "memory");
}

// 16B-chunk swizzle for h_lds (pitch 1032 shorts = 129 16B-chunks/row)
__device__ __forceinline__ int swz(int L) {
    return (L & 0x78) | (((L & 7) + (L >> 3)) & 7);
}

__global__ __launch_bounds__(256, 1) void esn_kernel(
    const float* __restrict__ x, const float* __restrict__ wih,
    const float* __restrict__ whh, const float* __restrict__ bih,
    const float* __restrict__ bhh, float* __restrict__ out,
    unsigned int* __restrict__ hbu0, unsigned int* __restrict__ hbu1)
{
    __shared__ __align__(16) unsigned short h_lds[16 * 1032];  // 33 KB
    __shared__ __align__(16) unsigned short x_lds[16 * 136];   // 4.25 KB

    const int tid  = threadIdx.x;
    const int lane = tid & 63;
    const int wv   = tid >> 6;
    const int col  = lane & 15;     // MFMA col (n) / A row (m)
    const int quad = lane >> 4;

    const int blk    = blockIdx.x;
    const int m      = blk >> 4;            // batch group 0..3
    const int m_base = m * 16;
    const int jj     = blk & 15;            // producer index within group
    const int n_idx  = jj * 4 + wv;
    const int n_base = n_idx * 16;

    // ---- one-time: weights into registers, hi/lo bf16 split ----
    bf16x8 bh[32], bl[32], ih_h[4], ih_l[4];
#pragma unroll
    for (int kt = 0; kt < 32; ++kt) {
        const float* p = whh + (size_t)(n_base + col) * HH + kt * 32 + quad * 8;
        bf16x8 hi, lo;
#pragma unroll
        for (int j = 0; j < 8; ++j) {
            float v = p[j];
            unsigned short h16 = f2bf(v);
            hi[j] = (short)h16;
            lo[j] = (short)f2bf(v - bf2f(h16));
        }
        bh[kt] = hi; bl[kt] = lo;
    }
#pragma unroll
    for (int kt = 0; kt < 4; ++kt) {
        const float* p = wih + (size_t)(n_base + col) * II + kt * 32 + quad * 8;
        bf16x8 hi, lo;
#pragma unroll
        for (int j = 0; j < 8; ++j) {
            float v = p[j];
            unsigned short h16 = f2bf(v);
            hi[j] = (short)h16;
            lo[j] = (short)f2bf(v - bf2f(h16));
        }
        ih_h[kt] = hi; ih_l[kt] = lo;
    }
    const float bias_sum = bih[n_base + col] + bhh[n_base + col];

    const int sr   = tid >> 4;        // x-staging row 0..15
    const int sc   = tid & 15;        // x-staging col group 0..15
    const int csrc = tid >> 4;        // h chunk this thread loads 0..15
    const int crow = tid & 15;        // row within that chunk

    // x software pipeline: prefetch x_0 into registers
    f32x4 xa, xb;
    {
        const float* gx = x + (size_t)(m_base + sr) * II + sc * 8;
        xa = *(const f32x4*)gx;
        xb = *(const f32x4*)(gx + 4);
    }

    for (int t = 0; t < TT; ++t) {
        const unsigned int* rbu = (t & 1) ? hbu1 : hbu0;
        unsigned int*       wbu = (t & 1) ? hbu0 : hbu1;
        // generation tags: producer at step s tags with 1^((s>>1)&1);
        // consumer at step t expects the tag of step t-1 (t=0: zero init).
        const unsigned int exp_tag =
            (t == 0) ? 0u : ((1u ^ (((unsigned)(t - 1) >> 1) & 1u)) << 30);
        const unsigned int my_tag = (1u ^ (((unsigned)t >> 1) & 1u)) << 30;

        // ---- issue h^t loads early (validated by tag check below) ----
        const unsigned int* gp =
            rbu + (size_t)(m * 16 + csrc) * 512 + crow * 32;
        u32x4 a0 = gload16_sc1(gp);
        u32x4 a1 = gload16_sc1(gp + 4);
        u32x4 a2 = gload16_sc1(gp + 8);
        u32x4 a3 = gload16_sc1(gp + 12);
        u32x4 a4 = gload16_sc1(gp + 16);
        u32x4 a5 = gload16_sc1(gp + 20);
        u32x4 a6 = gload16_sc1(gp + 24);
        u32x4 a7 = gload16_sc1(gp + 28);

        // convert prefetched x_t -> bf16 -> LDS
        {
            bf16x8 v;
#pragma unroll
            for (int j = 0; j < 4; ++j) v[j] = (short)f2bf(xa[j]);
#pragma unroll
            for (int j = 0; j < 4; ++j) v[4 + j] = (short)f2bf(xb[j]);
            *(bf16x8*)(x_lds + sr * 136 + sc * 8) = v;
        }
        // prefetch x_{t+1} (completes under the MFMA phases)
        if (t + 1 < TT) {
            const float* gx = x + (size_t)(t + 1) * (BB * II)
                              + (size_t)(m_base + sr) * II + sc * 8;
            xa = *(const f32x4*)gx;
            xb = *(const f32x4*)(gx + 4);
        }

        // barrier #1: x_lds ready. LDS-only wait — publish stores and the
        // h/x loads stay in flight across the barrier.
        asm volatile("s_waitcnt lgkmcnt(0)" ::: "memory");
        __builtin_amdgcn_s_barrier();
        __builtin_amdgcn_sched_barrier(0);

        // x MFMAs (independent of h) hide the h-load latency.
        f32x4 acc0 = {0.f, 0.f, 0.f, 0.f};   // hi-weight chain
        f32x4 acc1 = {0.f, 0.f, 0.f, 0.f};   // lo-weight chain
        const unsigned short* xrow = x_lds + col * 136;
#pragma unroll
        for (int kt = 0; kt < 4; ++kt) {
            bf16x8 a = *(const bf16x8*)(xrow + kt * 32 + quad * 8);
            acc0 = __builtin_amdgcn_mfma_f32_16x16x32_bf16(a, ih_h[kt], acc0, 0, 0, 0);
            acc1 = __builtin_amdgcn_mfma_f32_16x16x32_bf16(a, ih_l[kt], acc1, 0, 0, 0);
        }

        // ---- poll: wait loads, verify per-dword generation tags ----
        for (;;) {
            asm volatile("s_waitcnt vmcnt(0)"
                         : "+v"(a0), "+v"(a1), "+v"(a2), "+v"(a3),
                           "+v"(a4), "+v"(a5), "+v"(a6), "+v"(a7)
                         :: "memory");
            unsigned int bad;
            bad  = (a0[0] ^ exp_tag) | (a0[1] ^ exp_tag) | (a0[2] ^ exp_tag) | (a0[3] ^ exp_tag);
            bad |= (a1[0] ^ exp_tag) | (a1[1] ^ exp_tag) | (a1[2] ^ exp_tag) | (a1[3] ^ exp_tag);
            bad |= (a2[0] ^ exp_tag) | (a2[1] ^ exp_tag) | (a2[2] ^ exp_tag) | (a2[3] ^ exp_tag);
            bad |= (a3[0] ^ exp_tag) | (a3[1] ^ exp_tag) | (a3[2] ^ exp_tag) | (a3[3] ^ exp_tag);
            bad |= (a4[0] ^ exp_tag) | (a4[1] ^ exp_tag) | (a4[2] ^ exp_tag) | (a4[3] ^ exp_tag);
            bad |= (a5[0] ^ exp_tag) | (a5[1] ^ exp_tag) | (a5[2] ^ exp_tag) | (a5[3] ^ exp_tag);
            bad |= (a6[0] ^ exp_tag) | (a6[1] ^ exp_tag) | (a6[2] ^ exp_tag) | (a6[3] ^ exp_tag);
            bad |= (a7[0] ^ exp_tag) | (a7[1] ^ exp_tag) | (a7[2] ^ exp_tag) | (a7[3] ^ exp_tag);
            if (__all((bad & TAGBIT) == 0u)) break;
            a0 = gload16_sc1(gp);
            a1 = gload16_sc1(gp + 4);
            a2 = gload16_sc1(gp + 8);
            a3 = gload16_sc1(gp + 12);
            a4 = gload16_sc1(gp + 16);
            a5 = gload16_sc1(gp + 20);
            a6 = gload16_sc1(gp + 24);
            a7 = gload16_sc1(gp + 28);
        }

        // clear tag bits, write h_lds swizzled
        {
            unsigned short* lp = h_lds + crow * 1032;
            *(u32x4*)(lp + swz(csrc * 8 + 0) * 8) = a0 & 0xBFFFFFFFu;
            *(u32x4*)(lp + swz(csrc * 8 + 1) * 8) = a1 & 0xBFFFFFFFu;
            *(u32x4*)(lp + swz(csrc * 8 + 2) * 8) = a2 & 0xBFFFFFFFu;
            *(u32x4*)(lp + swz(csrc * 8 + 3) * 8) = a3 & 0xBFFFFFFFu;
            *(u32x4*)(lp + swz(csrc * 8 + 4) * 8) = a4 & 0xBFFFFFFFu;
            *(u32x4*)(lp + swz(csrc * 8 + 5) * 8) = a5 & 0xBFFFFFFFu;
            *(u32x4*)(lp + swz(csrc * 8 + 6) * 8) = a6 & 0xBFFFFFFFu;
            *(u32x4*)(lp + swz(csrc * 8 + 7) * 8) = a7 & 0xBFFFFFFFu;
        }
        // barrier #2: h_lds ready (LDS-only wait again)
        asm volatile("s_waitcnt lgkmcnt(0)" ::: "memory");
        __builtin_amdgcn_s_barrier();
        __builtin_amdgcn_sched_barrier(0);

        // hh MFMAs, dual independent chains
        const unsigned short* arow = h_lds + col * 1032;
#pragma unroll
        for (int kt = 0; kt < 32; ++kt) {
            bf16x8 a = *(const bf16x8*)(arow + swz(kt * 4 + quad) * 8);
            acc0 = __builtin_amdgcn_mfma_f32_16x16x32_bf16(a, bh[kt], acc0, 0, 0, 0);
            acc1 = __builtin_amdgcn_mfma_f32_16x16x32_bf16(a, bl[kt], acc1, 0, 0, 0);
        }

        // epilogue: bias + tanh
        float th[4];
#pragma unroll
        for (int i = 0; i < 4; ++i) {
            float pre = acc0[i] + acc1[i] + bias_sum;
            float pc  = fminf(fmaxf(pre, -9.f), 9.f);
            float e   = __expf(2.f * pc);
            th[i] = (e - 1.f) / (e + 1.f);
        }

        if (t == TT - 1) {
#pragma unroll
            for (int i = 0; i < 4; ++i)
                out[(size_t)(m_base + quad * 4 + i) * HH + n_base + col] = th[i];
        } else {
            // pack bf16 pairs (adjacent cols) into u32, tag, fire-and-forget
            unsigned int p01 = (unsigned int)f2bf(th[0]) |
                               ((unsigned int)f2bf(th[1]) << 16);
            unsigned int p23 = (unsigned int)f2bf(th[2]) |
                               ((unsigned int)f2bf(th[3]) << 16);
            unsigned int q01 = (unsigned int)__shfl_xor((int)p01, 1, 64);
            unsigned int q23 = (unsigned int)__shfl_xor((int)p23, 1, 64);
            if (!(lane & 1)) {
                unsigned int w0 = ((p01 & 0xFFFFu) | (q01 << 16)) | my_tag;
                unsigned int w1 = ((p01 >> 16) | (q01 & 0xFFFF0000u)) | my_tag;
                unsigned int w2 = ((p23 & 0xFFFFu) | (q23 << 16)) | my_tag;
                unsigned int w3 = ((p23 >> 16) | (q23 & 0xFFFF0000u)) | my_tag;
                unsigned int* bp = wbu + (size_t)(m * 16 + jj) * 512
                                   + wv * 8 + (col >> 1);
                gstore4_sc1(bp + (quad * 4 + 0) * 32, w0);
                gstore4_sc1(bp + (quad * 4 + 1) * 32, w1);
                gstore4_sc1(bp + (quad * 4 + 2) * 32, w2);
                gstore4_sc1(bp + (quad * 4 + 3) * 32, w3);
            }
            // no ack, no flag, no barrier: tags make the data self-validating
        }
    }
}

extern "C" void kernel_launch(void* const* d_in, const int* in_sizes, int n_in,
                              void* d_out, int out_size, void* d_ws, size_t ws_size,
                              hipStream_t stream) {
    const float* x   = (const float*)d_in[0];
    const float* wih = (const float*)d_in[1];
    const float* whh = (const float*)d_in[2];
    const float* bih = (const float*)d_in[3];
    const float* bhh = (const float*)d_in[4];
    float* out = (float*)d_out;

    unsigned int* hbu0 = (unsigned int*)d_ws;                      // 128 KB
    unsigned int* hbu1 = hbu0 + 32768;                             // 128 KB

    // zero both h buffers: h0 = 0 payload with tag bits 0 (ws poisoned 0xAA)
    hipMemsetAsync(d_ws, 0, 262144, stream);

    esn_kernel<<<dim3(64), dim3(256), 0, stream>>>(x, wih, whh, bih, bhh,
                                                   out, hbu0, hbu1);
}